// Round 6
// baseline (412.282 us; speedup 1.0000x reference)
//
#include <hip/hip_runtime.h>

#define TSEQ   512
#define BATCH  4096
#define MROWS  8      // batch rows per block; 512 blocks -> 2 independent blocks/CU

typedef short bf16x8 __attribute__((ext_vector_type(8)));
typedef float f32x4  __attribute__((ext_vector_type(4)));
typedef float f32x2  __attribute__((ext_vector_type(2)));

#define NL2E  (-1.44269504f)
#define P2L2E (2.88539008f)

__device__ __forceinline__ unsigned short f2bf(float f) {
    unsigned int u = __builtin_bit_cast(unsigned int, f);
    return (unsigned short)((u + 0x8000u) >> 16);
}

// Gate math for TWO cells at once, vectorized as f32x2 (v_pk_* fp32).
__device__ __forceinline__ f32x2 cellupd2(const f32x4 a, const f32x4 b, f32x2& C) {
    f32x2 ei = {__builtin_amdgcn_exp2f(a[0]), __builtin_amdgcn_exp2f(b[0])};
    f32x2 ef = {__builtin_amdgcn_exp2f(a[1]), __builtin_amdgcn_exp2f(b[1])};
    f32x2 eg = {__builtin_amdgcn_exp2f(a[2]), __builtin_amdgcn_exp2f(b[2])};
    f32x2 eo = {__builtin_amdgcn_exp2f(a[3]), __builtin_amdgcn_exp2f(b[3])};
    f32x2 A  = 1.f + ei;
    f32x2 G1 = eg + 1.f;
    f32x2 F  = 1.f + ef;
    f32x2 t  = A * G1;
    f32x2 G2 = eg * P2L2E + (NL2E * 2.f);
    f32x2 num = C * t + G2 * F;
    f32x2 den = t * F;
    f32x2 r  = {__builtin_amdgcn_rcpf(den.x), __builtin_amdgcn_rcpf(den.y)};
    f32x2 Cn = num * r;
    Cn.x = fminf(Cn.x, 126.f);
    Cn.y = fminf(Cn.y, 126.f);
    C = Cn;
    f32x2 ec = {__builtin_amdgcn_exp2f(Cn.x), __builtin_amdgcn_exp2f(Cn.y)};
    f32x2 B  = 1.f + eo;
    f32x2 hn = ec - 1.f;
    f32x2 hd = B * (ec + 1.f);
    f32x2 rr = {__builtin_amdgcn_rcpf(hd.x), __builtin_amdgcn_rcpf(hd.y)};
    return hn * rr;
}

// XOR-8 lane swap (within 32-lane halves): BitMode offset = (8<<10)|0x1F.
__device__ __forceinline__ f32x4 swz8(f32x4 v) {
    f32x4 r;
#pragma unroll
    for (int i = 0; i < 4; ++i)
        r[i] = __builtin_bit_cast(float,
                 __builtin_amdgcn_ds_swizzle(__builtin_bit_cast(int, v[i]), 0x201F));
    return r;
}

// ring/h2s: 16-col layout (cols 8..15 permanently ZERO -> safe MFMA B-cols),
// row = 64 bf16 = 128B, XOR swizzle byte ^= ((col&7)<<4) on write+read.
// xq: 64 slot-rows x 8 cols x 8 bf16 (16B frag) = 8KB, swizzle ^((t&7)<<4).
// 8 waves: wv 0..3 = L1, wv 4..7 = L2 (lag 1). Each wave computes 4 A-tiles
// (tt=0..3); acc[2],acc[3] are swapped to lanes col>=8 via ds_swizzle so every
// lane runs ONE cellupd2 on 2 real cells:
//   col<8 lane:  units 16lg+4wq+{0,1} of col
//   col>=8 lane: units 16lg+4wq+{2,3} of col-8

__global__ __launch_bounds__(512, 4) void lstm2_kernel(
    const float* __restrict__ x,
    const float* __restrict__ Wih0, const float* __restrict__ Whh0,
    const float* __restrict__ bih0, const float* __restrict__ bhh0,
    const float* __restrict__ Wih1, const float* __restrict__ Whh1,
    const float* __restrict__ bih1, const float* __restrict__ bhh1,
    const float* __restrict__ Wc1,  const float* __restrict__ bc1,
    const float* __restrict__ Wc2,  const float* __restrict__ bc2,
    float* __restrict__ out)
{
    __shared__ __align__(16) unsigned short ring[2][16 * 64];  // 4 KB
    __shared__ __align__(16) unsigned short h2s[2][16 * 64];   // 4 KB
    __shared__ __align__(16) unsigned short xq[64][64];        // 8 KB
    __shared__ float h2f[MROWS][65];
    __shared__ float hid[MROWS][33];

    const int tid  = threadIdx.x;
    const int wv   = tid >> 6;        // 0..7
    const int lane = tid & 63;
    const int col  = lane & 15;       // MFMA B/D column
    const int lg   = lane >> 4;       // k-group
    const int b0   = blockIdx.x * MROWS;
    const int sw   = (col & 7) << 4;
    const int colr = col & 7;         // real batch row owned after swizzle
    const int tsel = col >> 3;        // 0: tt{0,1}, 1: tt{2,3}
    const bool hi  = (col & 8) != 0;

    for (int i = tid; i < 1024; i += 512) {
        ((unsigned int*)ring)[i] = 0u;
        ((unsigned int*)h2s)[i]  = 0u;
    }

    // ---- x chunk 0 convert (xq rows 0..31) + chunk 1 prefetch: 256 threads ----
    const int xrow = (tid >> 5) & 7;  // 0..7
    const int xt   = tid & 31;        // chunk-local timestep
    const float* xb = x + ((size_t)(b0 + xrow) * TSEQ + xt) * 3;
    float xr0 = 0.f, xr1 = 0.f, xr2 = 0.f;
    if (tid < 256) {
        xr0 = xb[0]; xr1 = xb[1]; xr2 = xb[2];
        bf16x8 xf = {(short)f2bf(xr0),(short)f2bf(xr1),(short)f2bf(xr2),0,0,0,0,0};
        *(bf16x8*)((char*)xq + (xt << 7) + ((xrow << 4) ^ ((xt & 7) << 4))) = xf;
        xr0 = xb[96]; xr1 = xb[97]; xr2 = xb[98];
    }
    __syncthreads();

    const int rd0 = (col * 128 +      lg * 16) ^ sw;
    const int rd1 = (col * 128 + 64 + lg * 16) ^ sw;
    const int hwr = (colr * 128 + 32 * lg + 8 * (wv & 3) + 4 * tsel) ^ (colr << 4);

#define FLUSH(S) do { \
    if (((S) & 31) == 16 && (S) < 480) { \
        const int c1_ = ((S) >> 5) + 1; \
        const int t64_ = ((c1_ & 1) << 5) + xt; \
        bf16x8 xf_ = {(short)f2bf(xr0),(short)f2bf(xr1),(short)f2bf(xr2),0,0,0,0,0}; \
        *(bf16x8*)((char*)xq + (t64_ << 7) + ((xrow << 4) ^ ((xt & 7) << 4))) = xf_; \
        if (c1_ < 15) { const float* p_ = xb + (c1_ + 1) * 96; xr0 = p_[0]; xr1 = p_[1]; xr2 = p_[2]; } \
    } \
} while(0)

#define XQRD(S) (*(const bf16x8*)((const char*)xq + ((((S)&63)) << 7) + ((colr << 4) ^ (((S)&7) << 4))))
#define MM(A,B,C) __builtin_amdgcn_mfma_f32_16x16x32_bf16((A),(B),(C),0,0,0)

// post-MFMA: swap acc2/acc3 to hi lanes, select, update, pack+store
#define FINISH(A0,A1,A2,A3, CST, BUFBASE) do { \
        f32x4 s2_ = swz8(A2), s3_ = swz8(A3); \
        f32x4 sa_, sb_; \
        _Pragma("unroll") \
        for (int i_ = 0; i_ < 4; ++i_) { \
            sa_[i_] = hi ? s2_[i_] : A0[i_]; \
            sb_[i_] = hi ? s3_[i_] : A1[i_]; \
        } \
        hcur = cellupd2(sa_, sb_, CST); \
        unsigned int p0_; \
        asm("v_cvt_pk_bf16_f32 %0, %1, %2" : "=v"(p0_) : "v"(hcur.x), "v"(hcur.y)); \
        *(unsigned int*)((char*)(BUFBASE) + hwr) = p0_; \
    } while(0)

    if (wv < 4) {
        // ========== L1 waves: 4 A-tiles each (tt=0..3) ==========
        const int wq = wv;
        const int ga = col & 3;
        const float sca = (ga == 2) ? P2L2E : NL2E;
        bf16x8 Wf[4][3];
        f32x4 bia4[4];
#pragma unroll
        for (int tt = 0; tt < 4; ++tt) {
            const int n = ga * 64 + 16 * (col >> 2) + 4 * wq + tt;
#pragma unroll
            for (int f = 0; f < 3; ++f)
#pragma unroll
                for (int i = 0; i < 8; ++i) {
                    const int k = f * 32 + lg * 8 + i;
                    float v = 0.f;
                    if (k < 64)      v = Whh0[n * 64 + k];
                    else if (k < 67) v = Wih0[n * 3 + (k - 64)];
                    Wf[tt][f][i] = (short)f2bf(sca * v);
                }
#pragma unroll
            for (int r = 0; r < 4; ++r) {
                const int nb = r * 64 + 16 * lg + 4 * wq + tt;
                bia4[tt][r] = ((r == 2) ? P2L2E : NL2E) * (bih0[nb] + bhh0[nb]);
            }
        }
        f32x2 C01 = {0.f, 0.f};
        f32x2 hcur;
        bf16x8 pv2 = XQRD(0);

#define L1B(RI, WI, S) do { \
        const char* rb_ = (const char*)ring[RI]; \
        bf16x8 v0_ = *(const bf16x8*)(rb_ + rd0); \
        bf16x8 v1_ = *(const bf16x8*)(rb_ + rd1); \
        f32x4 a0_ = MM(Wf[0][2], pv2, bia4[0]); \
        f32x4 a1_ = MM(Wf[1][2], pv2, bia4[1]); \
        f32x4 a2_ = MM(Wf[2][2], pv2, bia4[2]); \
        f32x4 a3_ = MM(Wf[3][2], pv2, bia4[3]); \
        a0_ = MM(Wf[0][0], v0_, a0_);  a1_ = MM(Wf[1][0], v0_, a1_); \
        a2_ = MM(Wf[2][0], v0_, a2_);  a3_ = MM(Wf[3][0], v0_, a3_); \
        a0_ = MM(Wf[0][1], v1_, a0_);  a1_ = MM(Wf[1][1], v1_, a1_); \
        a2_ = MM(Wf[2][1], v1_, a2_);  a3_ = MM(Wf[3][1], v1_, a3_); \
        pv2 = XQRD((S) + 1); \
        FINISH(a0_, a1_, a2_, a3_, C01, ring[WI]); \
    } while(0)

        L1B(1, 0, 0);
        __syncthreads();                           // end slot 0
#pragma unroll 1
        for (int m = 0; m < 255; ++m) {
            const int s1 = 2 * m + 1;
            L1B(0, 1, s1);
            __syncthreads();                       // end odd slot
            L1B(1, 0, s1 + 1);
            FLUSH(s1 + 1);
            __syncthreads();                       // end even slot
        }
        L1B(0, 1, 511);
        __syncthreads();                           // end slot 511
        __syncthreads();                           // slot 512 idle
#undef L1B
    } else {
        // ========== L2 waves: lag 1; K = [h1(64) | h2(64)]; 4 A-tiles each ==========
        const int wq = wv - 4;
        const int ga = col & 3;
        const float sca = (ga == 2) ? P2L2E : NL2E;
        bf16x8 Wf[4][4];
        f32x4 bia4[4];
#pragma unroll
        for (int tt = 0; tt < 4; ++tt) {
            const int n = ga * 64 + 16 * (col >> 2) + 4 * wq + tt;
#pragma unroll
            for (int f = 0; f < 4; ++f)
#pragma unroll
                for (int i = 0; i < 8; ++i) {
                    const int k = f * 32 + lg * 8 + i;
                    const float v = (k < 64) ? Wih1[n * 64 + k] : Whh1[n * 64 + (k - 64)];
                    Wf[tt][f][i] = (short)f2bf(sca * v);
                }
#pragma unroll
            for (int r = 0; r < 4; ++r) {
                const int nb = r * 64 + 16 * lg + 4 * wq + tt;
                bia4[tt][r] = ((r == 2) ? P2L2E : NL2E) * (bih1[nb] + bhh1[nb]);
            }
        }
        f32x2 C01 = {0.f, 0.f};
        f32x2 hcur = {0.f, 0.f};

#define L2B(RB, HR) do { \
        const char* rb_ = (const char*)ring[RB]; \
        const char* hp_ = (const char*)h2s[HR]; \
        bf16x8 v0_ = *(const bf16x8*)(rb_ + rd0); \
        bf16x8 v1_ = *(const bf16x8*)(rb_ + rd1); \
        bf16x8 v2_ = *(const bf16x8*)(hp_ + rd0); \
        bf16x8 v3_ = *(const bf16x8*)(hp_ + rd1); \
        f32x4 c0_ = MM(Wf[0][0], v0_, bia4[0]); \
        f32x4 c1_ = MM(Wf[1][0], v0_, bia4[1]); \
        f32x4 c2_ = MM(Wf[2][0], v0_, bia4[2]); \
        f32x4 c3_ = MM(Wf[3][0], v0_, bia4[3]); \
        c0_ = MM(Wf[0][1], v1_, c0_);  c1_ = MM(Wf[1][1], v1_, c1_); \
        c2_ = MM(Wf[2][1], v1_, c2_);  c3_ = MM(Wf[3][1], v1_, c3_); \
        c0_ = MM(Wf[0][2], v2_, c0_);  c1_ = MM(Wf[1][2], v2_, c1_); \
        c2_ = MM(Wf[2][2], v2_, c2_);  c3_ = MM(Wf[3][2], v2_, c3_); \
        c0_ = MM(Wf[0][3], v3_, c0_);  c1_ = MM(Wf[1][3], v3_, c1_); \
        c2_ = MM(Wf[2][3], v3_, c2_);  c3_ = MM(Wf[3][3], v3_, c3_); \
        FINISH(c0_, c1_, c2_, c3_, C01, h2s[RB]); \
    } while(0)

        __syncthreads();                           // slot 0 idle
#pragma unroll 1
        for (int m = 0; m < 255; ++m) {
            L2B(0, 1);                             // slot 2m+1, t=2m
            __syncthreads();
            L2B(1, 0);                             // slot 2m+2, t=2m+1
            __syncthreads();
        }
        L2B(0, 1);                                 // slot 511, t=510
        __syncthreads();
        L2B(1, 0);                                 // slot 512, t=511
        __syncthreads();
#undef L2B
        const int ub = 16 * lg + 4 * wq + 2 * tsel;
        h2f[colr][ub + 0] = hcur.x;
        h2f[colr][ub + 1] = hcur.y;
    }
    __syncthreads();

    // ================= classifier head =================
    if (tid < 256) {
        const int b = tid & 7, j = tid >> 3;       // j 0..31
        float s = bc1[j];
#pragma unroll 8
        for (int k = 0; k < 64; ++k) s += Wc1[j * 64 + k] * h2f[b][k];
        hid[b][j] = fmaxf(s, 0.f);
    }
    __syncthreads();
    if (tid < MROWS) {
        float s = bc2[0];
#pragma unroll 8
        for (int k = 0; k < 32; ++k) s += Wc2[k] * hid[tid][k];
        float e = __builtin_amdgcn_exp2f(NL2E * s);
        out[b0 + tid] = __builtin_amdgcn_rcpf(1.f + e);
    }
}

extern "C" void kernel_launch(void* const* d_in, const int* in_sizes, int n_in,
                              void* d_out, int out_size, void* d_ws, size_t ws_size,
                              hipStream_t stream) {
    lstm2_kernel<<<BATCH / MROWS, 512, 0, stream>>>(
        (const float*)d_in[0],
        (const float*)d_in[1], (const float*)d_in[2],
        (const float*)d_in[3], (const float*)d_in[4],
        (const float*)d_in[5], (const float*)d_in[6],
        (const float*)d_in[7], (const float*)d_in[8],
        (const float*)d_in[9], (const float*)d_in[10],
        (const float*)d_in[11], (const float*)d_in[12],
        (float*)d_out);
}

// Round 7
// 288.458 us; speedup vs baseline: 1.4293x; 1.4293x over previous
//
#include <hip/hip_runtime.h>

#define TSEQ   512
#define BATCH  4096
#define MROWS  16

typedef short bf16x8 __attribute__((ext_vector_type(8)));
typedef float f32x4  __attribute__((ext_vector_type(4)));
typedef float f32x2  __attribute__((ext_vector_type(2)));

#define NL2E  (-1.44269504f)
#define P2L2E (2.88539008f)

__device__ __forceinline__ unsigned short f2bf(float f) {
    unsigned int u = __builtin_bit_cast(unsigned int, f);
    return (unsigned short)((u + 0x8000u) >> 16);
}

// Memory-k position -> true unit index. h rows in ring/h2s are stored
// permuted so that lane (col,lg) of wave wq writes its unit pair at dword
// q = 4*wq + lg  => write banks spread over all 32 (was: 8 banks, wq-uniform).
// unit(2q+b) = 16*(q&3) + 2*(q>>2) + b.
__device__ __forceinline__ int uperm(int p) {
    return 16 * ((p >> 1) & 3) + 2 * (p >> 3) + (p & 1);
}

// Gate math for TWO cells at once, vectorized as f32x2 (v_pk_* fp32).
// a,b pre-scaled accs: exp2(a0)=e^-i, exp2(a1)=e^-f, exp2(a2)=e^{2g},
// exp2(a3)=e^-o. C = cell-state pair scaled by 2*log2e.
__device__ __forceinline__ f32x2 cellupd2(const f32x4 a, const f32x4 b, f32x2& C) {
    f32x2 ei = {__builtin_amdgcn_exp2f(a[0]), __builtin_amdgcn_exp2f(b[0])};
    f32x2 ef = {__builtin_amdgcn_exp2f(a[1]), __builtin_amdgcn_exp2f(b[1])};
    f32x2 eg = {__builtin_amdgcn_exp2f(a[2]), __builtin_amdgcn_exp2f(b[2])};
    f32x2 eo = {__builtin_amdgcn_exp2f(a[3]), __builtin_amdgcn_exp2f(b[3])};
    f32x2 A  = 1.f + ei;
    f32x2 G1 = eg + 1.f;
    f32x2 F  = 1.f + ef;
    f32x2 t  = A * G1;
    f32x2 G2 = eg * P2L2E + (NL2E * 2.f);
    f32x2 num = C * t + G2 * F;
    f32x2 den = t * F;
    f32x2 r  = {__builtin_amdgcn_rcpf(den.x), __builtin_amdgcn_rcpf(den.y)};
    f32x2 Cn = num * r;
    Cn.x = fminf(Cn.x, 126.f);
    Cn.y = fminf(Cn.y, 126.f);
    C = Cn;
    f32x2 ec = {__builtin_amdgcn_exp2f(Cn.x), __builtin_amdgcn_exp2f(Cn.y)};
    f32x2 B  = 1.f + eo;
    f32x2 hn = ec - 1.f;
    f32x2 hd = B * (ec + 1.f);
    f32x2 rr = {__builtin_amdgcn_rcpf(hd.x), __builtin_amdgcn_rcpf(hd.y)};
    return hn * rr;
}

// ring/h2s rows: 64 bf16 = 128B (unit-permuted), XOR swizzle byte ^= ((col&7)<<4).
// xq: 64 slot-rows x 16 cols x 8 bf16 (16B frag), swizzle byte ^= ((t64&7)<<4).
// 16 waves: wv 0..7 = L1 (2 units/lane), wv 8..15 = L2 (lag 1).

__global__ __launch_bounds__(1024, 4) void lstm2_kernel(
    const float* __restrict__ x,
    const float* __restrict__ Wih0, const float* __restrict__ Whh0,
    const float* __restrict__ bih0, const float* __restrict__ bhh0,
    const float* __restrict__ Wih1, const float* __restrict__ Whh1,
    const float* __restrict__ bih1, const float* __restrict__ bhh1,
    const float* __restrict__ Wc1,  const float* __restrict__ bc1,
    const float* __restrict__ Wc2,  const float* __restrict__ bc2,
    float* __restrict__ out)
{
    __shared__ __align__(16) unsigned short ring[2][MROWS * 64];
    __shared__ __align__(16) unsigned short h2s[2][MROWS * 64];
    __shared__ __align__(16) unsigned short xq[64][128];   // 16 KB
    __shared__ float h2f[MROWS][65];
    __shared__ float hid[MROWS][33];

    const int tid  = threadIdx.x;
    const int wv   = tid >> 6;        // 0..15
    const int lane = tid & 63;
    const int col  = lane & 15;       // batch index (B-operand col / A-row)
    const int lg   = lane >> 4;       // k-group
    const int b0   = blockIdx.x * MROWS;
    const int sw   = (col & 7) << 4;

    ((unsigned int*)ring)[tid] = 0u;
    ((unsigned int*)h2s)[tid]  = 0u;

    // ---- x chunk 0 convert (into xq rows 0..31) + chunk 1 prefetch ----
    const int xrow = (tid >> 5) & 15;
    const int xt   = tid & 31;        // chunk-local timestep
    const float* xb = x + ((size_t)(b0 + xrow) * TSEQ + xt) * 3;
    float xr0 = 0.f, xr1 = 0.f, xr2 = 0.f;
    if (tid < 512) {
        xr0 = xb[0]; xr1 = xb[1]; xr2 = xb[2];
        bf16x8 xf = {(short)f2bf(xr0),(short)f2bf(xr1),(short)f2bf(xr2),0,0,0,0,0};
        *(bf16x8*)((char*)xq + (xt << 8) + ((xrow << 4) ^ ((xt & 7) << 4))) = xf;
        xr0 = xb[96]; xr1 = xb[97]; xr2 = xb[98];
    }
    __syncthreads();

    const int rd0 = (col * 128 +      lg * 16) ^ sw;
    const int rd1 = (col * 128 + 64 + lg * 16) ^ sw;

#define FLUSH(S) do { \
    if (((S) & 31) == 16 && (S) < 480) { \
        const int c1_ = ((S) >> 5) + 1; \
        const int t64_ = ((c1_ & 1) << 5) + xt; \
        bf16x8 xf_ = {(short)f2bf(xr0),(short)f2bf(xr1),(short)f2bf(xr2),0,0,0,0,0}; \
        *(bf16x8*)((char*)xq + (t64_ << 8) + ((xrow << 4) ^ ((xt & 7) << 4))) = xf_; \
        if (c1_ < 15) { const float* p_ = xb + (c1_ + 1) * 96; xr0 = p_[0]; xr1 = p_[1]; xr2 = p_[2]; } \
    } \
} while(0)

#define XQRD(S) (*(const bf16x8*)((const char*)xq + ((((S)&63)) << 8) + ((col << 4) ^ (((S)&7) << 4))))
#define MM(A,B,C) __builtin_amdgcn_mfma_f32_16x16x32_bf16((A),(B),(C),0,0,0)

    if (wv < 8) {
        // ========== L1 waves: lane owns units u = 16*lg + 2*wq + {0,1} ==========
        const int wq = wv;
        const int ga = col & 3;
        const float sca = (ga == 2) ? P2L2E : NL2E;
        bf16x8 Wf[2][3];
        f32x4 bia4[2];
#pragma unroll
        for (int tt = 0; tt < 2; ++tt) {
            const int n = ga * 64 + 16 * (col >> 2) + 2 * wq + tt;
#pragma unroll
            for (int f = 0; f < 3; ++f)
#pragma unroll
                for (int i = 0; i < 8; ++i) {
                    const int k = f * 32 + lg * 8 + i;
                    float v = 0.f;
                    if (k < 64)      v = Whh0[n * 64 + uperm(k)];
                    else if (k < 67) v = Wih0[n * 3 + (k - 64)];
                    Wf[tt][f][i] = (short)f2bf(sca * v);
                }
#pragma unroll
            for (int r = 0; r < 4; ++r) {
                const int nb = r * 64 + 16 * lg + 2 * wq + tt;
                bia4[tt][r] = ((r == 2) ? P2L2E : NL2E) * (bih0[nb] + bhh0[nb]);
            }
        }
        const int hw = (col * 128 + 16 * wq + 4 * lg) ^ sw;   // dword q = 4wq+lg
        f32x2 C01 = {0.f, 0.f};
        bf16x8 pv2 = XQRD(0);

// x-MFMA first (prefetched operand, zero wait), then ring reads.
#define L1B(RI, WI, S) do { \
        const char* rb_ = (const char*)ring[RI]; \
        bf16x8 v0_ = *(const bf16x8*)(rb_ + rd0); \
        bf16x8 v1_ = *(const bf16x8*)(rb_ + rd1); \
        __builtin_amdgcn_s_setprio(1); \
        f32x4 a0_ = MM(Wf[0][2], pv2, bia4[0]); \
        f32x4 a1_ = MM(Wf[1][2], pv2, bia4[1]); \
        a0_ = MM(Wf[0][0], v0_, a0_); \
        a1_ = MM(Wf[1][0], v0_, a1_); \
        a0_ = MM(Wf[0][1], v1_, a0_); \
        a1_ = MM(Wf[1][1], v1_, a1_); \
        pv2 = XQRD((S) + 1); \
        f32x2 h01_ = cellupd2(a0_, a1_, C01); \
        unsigned int p0_; \
        asm("v_cvt_pk_bf16_f32 %0, %1, %2" : "=v"(p0_) : "v"(h01_.x), "v"(h01_.y)); \
        *(unsigned int*)((char*)ring[WI] + hw) = p0_; \
        __builtin_amdgcn_s_setprio(0); \
    } while(0)

        L1B(1, 0, 0);
        __syncthreads();                           // end slot 0
#pragma unroll 1
        for (int m = 0; m < 255; ++m) {
            const int s1 = 2 * m + 1;
            L1B(0, 1, s1);
            __syncthreads();                       // end odd slot
            FLUSH(s1 + 1);
            L1B(1, 0, s1 + 1);
            __syncthreads();                       // end even slot
        }
        L1B(0, 1, 511);
        __syncthreads();                           // end slot 511
        __syncthreads();                           // slot 512 idle
#undef L1B
    } else {
        // ========== L2 waves: lag 1; K = [h1(64) | h2(64)]; units 16*lg+2*wq+{0,1} ==========
        const int wq = wv - 8;
        const int ga = col & 3;
        const float sca = (ga == 2) ? P2L2E : NL2E;
        bf16x8 Wf[2][4];
        f32x4 bia4[2];
#pragma unroll
        for (int tt = 0; tt < 2; ++tt) {
            const int n = ga * 64 + 16 * (col >> 2) + 2 * wq + tt;
#pragma unroll
            for (int f = 0; f < 4; ++f)
#pragma unroll
                for (int i = 0; i < 8; ++i) {
                    const int k = f * 32 + lg * 8 + i;
                    const float v = (k < 64) ? Wih1[n * 64 + uperm(k)]
                                             : Whh1[n * 64 + uperm(k - 64)];
                    Wf[tt][f][i] = (short)f2bf(sca * v);
                }
#pragma unroll
            for (int r = 0; r < 4; ++r) {
                const int nb = r * 64 + 16 * lg + 2 * wq + tt;
                bia4[tt][r] = ((r == 2) ? P2L2E : NL2E) * (bih1[nb] + bhh1[nb]);
            }
        }
        const int hw2 = (col * 128 + 16 * wq + 4 * lg) ^ sw;  // dword q = 4wq+lg
        f32x2 C01 = {0.f, 0.f};
        f32x2 hv01 = {0.f, 0.f};

#define L2B(RB, HR) do { \
        const char* rb_ = (const char*)ring[RB]; \
        const char* hp_ = (const char*)h2s[HR]; \
        bf16x8 v0_ = *(const bf16x8*)(rb_ + rd0); \
        bf16x8 v1_ = *(const bf16x8*)(rb_ + rd1); \
        bf16x8 v2_ = *(const bf16x8*)(hp_ + rd0); \
        bf16x8 v3_ = *(const bf16x8*)(hp_ + rd1); \
        __builtin_amdgcn_s_setprio(1); \
        f32x4 a0_ = MM(Wf[0][0], v0_, bia4[0]); \
        f32x4 a1_ = MM(Wf[1][0], v0_, bia4[1]); \
        a0_ = MM(Wf[0][1], v1_, a0_); \
        a1_ = MM(Wf[1][1], v1_, a1_); \
        a0_ = MM(Wf[0][2], v2_, a0_); \
        a1_ = MM(Wf[1][2], v2_, a1_); \
        a0_ = MM(Wf[0][3], v3_, a0_); \
        a1_ = MM(Wf[1][3], v3_, a1_); \
        hv01 = cellupd2(a0_, a1_, C01); \
        unsigned int p0_; \
        asm("v_cvt_pk_bf16_f32 %0, %1, %2" : "=v"(p0_) : "v"(hv01.x), "v"(hv01.y)); \
        *(unsigned int*)((char*)h2s[RB] + hw2) = p0_; \
        __builtin_amdgcn_s_setprio(0); \
    } while(0)

        __syncthreads();                           // slot 0 idle
#pragma unroll 1
        for (int m = 0; m < 255; ++m) {
            L2B(0, 1);                             // slot 2m+1, t=2m
            __syncthreads();
            L2B(1, 0);                             // slot 2m+2, t=2m+1
            __syncthreads();
        }
        L2B(0, 1);                                 // slot 511, t=510
        __syncthreads();
        L2B(1, 0);                                 // slot 512, t=511
        __syncthreads();
#undef L2B
        const int ub = 16 * lg + 2 * wq;
        h2f[col][ub + 0] = hv01.x;
        h2f[col][ub + 1] = hv01.y;
    }
    __syncthreads();

    // ================= classifier head =================
    if (tid < 512) {
        const int b = tid & 15, j = tid >> 4;      // j 0..31
        float s = bc1[j];
#pragma unroll 8
        for (int k = 0; k < 64; ++k) s += Wc1[j * 64 + k] * h2f[b][k];
        hid[b][j] = fmaxf(s, 0.f);
    }
    __syncthreads();
    if (tid < 16) {
        float s = bc2[0];
#pragma unroll 8
        for (int k = 0; k < 32; ++k) s += Wc2[k] * hid[tid][k];
        float e = __builtin_amdgcn_exp2f(NL2E * s);
        out[b0 + tid] = __builtin_amdgcn_rcpf(1.f + e);
    }
}

extern "C" void kernel_launch(void* const* d_in, const int* in_sizes, int n_in,
                              void* d_out, int out_size, void* d_ws, size_t ws_size,
                              hipStream_t stream) {
    lstm2_kernel<<<BATCH / MROWS, 1024, 0, stream>>>(
        (const float*)d_in[0],
        (const float*)d_in[1], (const float*)d_in[2],
        (const float*)d_in[3], (const float*)d_in[4],
        (const float*)d_in[5], (const float*)d_in[6],
        (const float*)d_in[7], (const float*)d_in[8],
        (const float*)d_in[9], (const float*)d_in[10],
        (const float*)d_in[11], (const float*)d_in[12],
        (float*)d_out);
}